// Round 1
// baseline (659.894 us; speedup 1.0000x reference)
//
#include <hip/hip_runtime.h>
#include <math.h>

// n is fixed by the problem: angles has n(n-1)/2 = 2016 -> n = 64.
#define N 64
#define NPAIRS (N * (N - 1) / 2)  // 2016
#define NSEG 8
#define SEGLEN (NPAIRS / NSEG)    // 252
#define STJ 68                    // padded stride (floats) for transposed segment tile

// ---------------------------------------------------------------------------
// Segment application: apply rotations k in [LO, HI) to this lane's column.
// LO/HI are template constants so the guard folds at compile time: each
// instantiation is ~252 rotations of straight-line code (~10 KB), so each
// wave only streams its own 1/8 of the instruction footprint.
// ---------------------------------------------------------------------------
template <int LO, int HI>
__device__ __forceinline__ void apply_seg(float col[N], const float2* cs) {
  int k = 0;
#pragma unroll
  for (int t = 0; t < N - 1; ++t) {
#pragma unroll
    for (int b = t + 1; b < N; ++b) {
      if (k >= LO && k < HI) {  // compile-time constant per unrolled iter
        float2 p = cs[k];       // p.x = cos, p.y = sin
        float rt = col[t];
        float rb = col[b];
        col[t] = fmaf(p.x, rt, -p.y * rb);
        col[b] = fmaf(p.y, rt, p.x * rb);
      }
      ++k;
    }
  }
}

// ---------------------------------------------------------------------------
// Kernel 1: build R^T (scaled by mus) from the Givens angle sequence.
// 512 threads (8 waves), 1 block.
//   Phase 1: wave w computes segment product S_w = G_{(w+1)*252-1}..G_{w*252}
//            (one column per lane, registers, compile-time unrolled).
//   Phase 2: sequential combine P <- S_w * P for w = 1..7. Each multiply
//            uses all 512 threads: thread (wid,lane) computes rows
//            [wid*8, wid*8+8) of column `lane`. S_w is staged transposed in
//            LDS so its rows are read as uniform (broadcast) ds_read_b128.
// Output layout: RT[j*64 + i] = mus[i] * R[i][j].
// ---------------------------------------------------------------------------
__global__ __launch_bounds__(512) void build_r_kernel(
    const float* __restrict__ angles, const float* __restrict__ mus,
    float* __restrict__ RT) {
  __shared__ float2 cs[NPAIRS];   // 16128 B
  __shared__ float P[N * N];      // running product, P[k*64 + j]   (16384 B)
  __shared__ float ST[N * STJ];   // S_w transposed: ST[k*STJ + i]  (17408 B)

  const int tid = threadIdx.x;
  const int lane = tid & 63;
  const int wid = tid >> 6;

  // Parallel sincos across all 512 threads.
  for (int k = tid; k < NPAIRS; k += 512) {
    float s, c;
    sincosf(angles[k], &s, &c);
    cs[k] = make_float2(c, s);
  }
  __syncthreads();

  // ---- Phase 1: per-wave segment product, one column per lane ----
  float col[N];
#pragma unroll
  for (int i = 0; i < N; ++i) col[i] = (i == lane) ? 1.0f : 0.0f;

  switch (wid) {
    case 0: apply_seg<0 * SEGLEN, 1 * SEGLEN>(col, cs); break;
    case 1: apply_seg<1 * SEGLEN, 2 * SEGLEN>(col, cs); break;
    case 2: apply_seg<2 * SEGLEN, 3 * SEGLEN>(col, cs); break;
    case 3: apply_seg<3 * SEGLEN, 4 * SEGLEN>(col, cs); break;
    case 4: apply_seg<4 * SEGLEN, 5 * SEGLEN>(col, cs); break;
    case 5: apply_seg<5 * SEGLEN, 6 * SEGLEN>(col, cs); break;
    case 6: apply_seg<6 * SEGLEN, 7 * SEGLEN>(col, cs); break;
    case 7: apply_seg<7 * SEGLEN, 8 * SEGLEN>(col, cs); break;
  }

  // ---- Phase 2: P <- S_0, then P <- S_w * P for w = 1..7 ----
  if (wid == 0) {
#pragma unroll
    for (int i = 0; i < N; ++i) P[i * N + lane] = col[i];  // stride-1 lanes: conflict-free
  }
  __syncthreads();

  const int i0 = wid * 8;
  float acc[8];
#pragma unroll
  for (int u = 0; u < 8; ++u) acc[u] = 0.0f;

  for (int w = 1; w < NSEG; ++w) {
    // Wave w dumps its segment, transposed: ST[k][i] = S_w[i][k].
    // Lane holds column `lane` -> writes row `lane` of ST (contiguous).
    if (wid == w) {
#pragma unroll
      for (int u = 0; u < N / 4; ++u) {
        *(float4*)&ST[lane * STJ + u * 4] =
            make_float4(col[4 * u], col[4 * u + 1], col[4 * u + 2], col[4 * u + 3]);
      }
    }
    __syncthreads();

    // C = S_w * P ; thread computes C[i0..i0+8)[lane].
#pragma unroll
    for (int u = 0; u < 8; ++u) acc[u] = 0.0f;
#pragma unroll 4
    for (int k = 0; k < N; ++k) {
      float bkj = P[k * N + lane];                       // stride-1: conflict-free
      float4 a0 = *(const float4*)&ST[k * STJ + i0];     // uniform: broadcast
      float4 a1 = *(const float4*)&ST[k * STJ + i0 + 4]; // uniform: broadcast
      acc[0] = fmaf(a0.x, bkj, acc[0]);
      acc[1] = fmaf(a0.y, bkj, acc[1]);
      acc[2] = fmaf(a0.z, bkj, acc[2]);
      acc[3] = fmaf(a0.w, bkj, acc[3]);
      acc[4] = fmaf(a1.x, bkj, acc[4]);
      acc[5] = fmaf(a1.y, bkj, acc[5]);
      acc[6] = fmaf(a1.z, bkj, acc[6]);
      acc[7] = fmaf(a1.w, bkj, acc[7]);
    }
    __syncthreads();
#pragma unroll
    for (int u = 0; u < 8; ++u) P[(i0 + u) * N + lane] = acc[u];
    __syncthreads();
  }

  // acc now holds final R rows [i0, i0+8) of column `lane`.
  // RT[j][i] = mus[i] * R[i][j]
#pragma unroll
  for (int u = 0; u < 8; ++u) {
    const int i = i0 + u;
    RT[lane * N + i] = mus[i] * acc[u];
  }
}

// ---------------------------------------------------------------------------
// Kernel 2: out[i][j] = sum_k R[i][k] * X[k][j].
// One column j per thread; 64 fp32 accumulators in VGPRs.
// RT staged once per block into LDS -> the inner loop's R reads are uniform
// ds_read_b128 broadcasts (frees the VMEM pipe for the streaming X loads).
// X loads / out stores: nontemporal (each byte touched exactly once).
// ---------------------------------------------------------------------------
__global__ __launch_bounds__(256) void apply_r_kernel(
    const float* __restrict__ X, const float* __restrict__ RT,
    float* __restrict__ out, int m) {
  __shared__ float Rs[N * N];  // 16 KB

  const int tid = threadIdx.x;
  {
    const float4* __restrict__ src = (const float4*)RT;
    float4* dst = (float4*)Rs;
#pragma unroll
    for (int u = 0; u < 4; ++u) dst[u * 256 + tid] = src[u * 256 + tid];
  }
  __syncthreads();

  const int j = blockIdx.x * 256 + tid;
  if (j >= m) return;

  float acc[N];
#pragma unroll
  for (int i = 0; i < N; ++i) acc[i] = 0.0f;

  const float* xp = X + j;
#pragma unroll 8
  for (int k = 0; k < N; ++k) {
    const float x = __builtin_nontemporal_load(xp + (size_t)k * m);
    const float4* r4 = (const float4*)(Rs + k * N);
#pragma unroll
    for (int ii = 0; ii < N / 4; ++ii) {
      float4 r = r4[ii];
      acc[ii * 4 + 0] = fmaf(r.x, x, acc[ii * 4 + 0]);
      acc[ii * 4 + 1] = fmaf(r.y, x, acc[ii * 4 + 1]);
      acc[ii * 4 + 2] = fmaf(r.z, x, acc[ii * 4 + 2]);
      acc[ii * 4 + 3] = fmaf(r.w, x, acc[ii * 4 + 3]);
    }
  }

#pragma unroll
  for (int i = 0; i < N; ++i) {
    __builtin_nontemporal_store(acc[i], out + (size_t)i * m + j);
  }
}

extern "C" void kernel_launch(void* const* d_in, const int* in_sizes, int n_in,
                              void* d_out, int out_size, void* d_ws,
                              size_t ws_size, hipStream_t stream) {
  const float* X = (const float*)d_in[0];       // 64 x m fp32
  const float* angles = (const float*)d_in[1];  // 2016 fp32
  const float* mus = (const float*)d_in[2];     // 64 fp32
  float* out = (float*)d_out;                   // 64 x m fp32
  float* RT = (float*)d_ws;                     // 64*64 fp32 scratch (16 KB)

  const int m = in_sizes[0] / N;

  build_r_kernel<<<1, 512, 0, stream>>>(angles, mus, RT);

  const int blocks = (m + 255) / 256;
  apply_r_kernel<<<blocks, 256, 0, stream>>>(X, RT, out, m);
}